// Round 1
// baseline (368.990 us; speedup 1.0000x reference)
//
#include <hip/hip_runtime.h>

#define NIMG 256
#define CIN  256
#define PIX  784
#define DD   64
#define NP   200
#define NPP  208   // prototypes padded to 13*16
#define NCLS 10

#define XS 264     // row stride (bf16 elems) for xlds / w1lds (256 + 8 pad, keeps 16B align)
#define HS 72      // row stride for htile/ftile/w2lds/protolds (64 + 8 pad)

typedef __attribute__((ext_vector_type(8))) short bf16x8;
typedef __attribute__((ext_vector_type(4))) float f32x4;

__device__ __forceinline__ unsigned short f2bf(float f) {
    union { float f; unsigned int u; } v; v.f = f;
    unsigned int r = v.u + 0x7fffu + ((v.u >> 16) & 1u);   // RNE
    return (unsigned short)(r >> 16);
}
__device__ __forceinline__ float bf2f(unsigned short h) {
    union { float f; unsigned int u; } v; v.u = ((unsigned int)h) << 16;
    return v.f;
}

__global__ __launch_bounds__(512)
void proto_fused_kernel(const float* __restrict__ x,
                        const float* __restrict__ W1, const float* __restrict__ b1,
                        const float* __restrict__ W2, const float* __restrict__ b2,
                        const float* __restrict__ proto,
                        const float* __restrict__ lastW, const float* __restrict__ lastb,
                        float* __restrict__ out)
{
    __shared__ __align__(16) unsigned short xlds[64 * XS];      // 33.8 KB, [px][c]
    __shared__ __align__(16) unsigned short w1lds[64 * XS];     // 33.8 KB, [o][c]
    __shared__ __align__(16) unsigned short w2lds[64 * HS];     //  9.2 KB, [o][c]
    __shared__ __align__(16) unsigned short protolds[NPP * HS]; // 30.0 KB, [p][d]
    __shared__ __align__(16) unsigned short htile[64 * HS];     //  9.2 KB, [px][d]
    __shared__ __align__(16) unsigned short ftile[64 * HS];     //  9.2 KB, [px][d]
    __shared__ float p2lds[NPP];
    __shared__ float s2lds[64];
    __shared__ float b1lds[DD], b2lds[DD];
    __shared__ unsigned int bmin[NPP];

    const int n    = blockIdx.x;
    const int t    = threadIdx.x;
    const int wave = t >> 6;
    const int lane = t & 63;
    const int q    = lane >> 4;     // quad row within wave
    const int l15  = lane & 15;
    const int s    = wave & 3;      // pixel strip (16 px) within 64-px tile
    const int dh   = wave >> 2;     // which half of the N-tiles this wave owns

    // ---------------- one-time staging ----------------
    for (int i = 0; i < 32; ++i) {               // W1: 64x256
        int idx = t + i * 512;
        w1lds[(idx >> 8) * XS + (idx & 255)] = f2bf(W1[idx]);
    }
    for (int i = 0; i < 8; ++i) {                // W2: 64x64
        int idx = t + i * 512;
        w2lds[(idx >> 6) * HS + (idx & 63)] = f2bf(W2[idx]);
    }
    for (int i = 0; i < 25; ++i) {               // prototypes: 200x64 (25*512 == 12800 exactly)
        int idx = t + i * 512;
        protolds[(idx >> 6) * HS + (idx & 63)] = f2bf(proto[idx]);
    }
    {   // zero pad prototype rows 200..207
        int p = NP + (t >> 6), d = t & 63;
        protolds[p * HS + d] = 0;
    }
    if (t < DD) { b1lds[t] = b1[t]; b2lds[t] = b2[t]; }
    if (t < NPP) {
        float acc = 0.f;
        if (t < NP) {
            for (int d = 0; d < DD; ++d) { float v = proto[t * DD + d]; acc += v * v; }
        }
        p2lds[t] = acc;
        bmin[t] = 0x7f800000u;   // +inf bits (dist >= 0 so uint order == float order)
    }

    // ---------------- main loop over 13 pixel tiles of 64 ----------------
    for (int tile = 0; tile < 13; ++tile) {
        const int px0 = tile * 64;

        // ---- stage x tile: global fp32 [c][px] -> LDS bf16 [px][c] ----
        {
            const int p4    = (t & 15) * 4;      // 4 consecutive pixels
            const int cbase = t >> 4;            // 0..31
            for (int i = 0; i < 8; ++i) {
                int c = cbase + i * 32;
                const float* src = x + ((size_t)n * CIN + c) * PIX + px0 + p4;
                float v0, v1, v2, v3;
                if (px0 + p4 + 3 < PIX) {
                    float4 v = *(const float4*)src;
                    v0 = v.x; v1 = v.y; v2 = v.z; v3 = v.w;
                } else {
                    v0 = (px0 + p4 + 0 < PIX) ? src[0] : 0.f;
                    v1 = (px0 + p4 + 1 < PIX) ? src[1] : 0.f;
                    v2 = (px0 + p4 + 2 < PIX) ? src[2] : 0.f;
                    v3 = (px0 + p4 + 3 < PIX) ? src[3] : 0.f;
                }
                xlds[(p4 + 0) * XS + c] = f2bf(v0);
                xlds[(p4 + 1) * XS + c] = f2bf(v1);
                xlds[(p4 + 2) * XS + c] = f2bf(v2);
                xlds[(p4 + 3) * XS + c] = f2bf(v3);
            }
        }
        __syncthreads();

        // ---- GEMM1: H[px][o] = sum_c x[px][c] * W1[o][c], + b1, ReLU ----
        {
            const int dt0 = dh * 2, dt1 = dh * 2 + 1;
            f32x4 acc0 = {0.f, 0.f, 0.f, 0.f}, acc1 = {0.f, 0.f, 0.f, 0.f};
            const int arow  = (s * 16 + l15) * XS + q * 8;
            const int brow0 = (dt0 * 16 + l15) * XS + q * 8;
            const int brow1 = (dt1 * 16 + l15) * XS + q * 8;
            for (int kk = 0; kk < 256; kk += 32) {
                bf16x8 a   = *(const bf16x8*)&xlds[arow + kk];
                bf16x8 bb0 = *(const bf16x8*)&w1lds[brow0 + kk];
                bf16x8 bb1 = *(const bf16x8*)&w1lds[brow1 + kk];
                acc0 = __builtin_amdgcn_mfma_f32_16x16x32_bf16(a, bb0, acc0, 0, 0, 0);
                acc1 = __builtin_amdgcn_mfma_f32_16x16x32_bf16(a, bb1, acc1, 0, 0, 0);
            }
            for (int r = 0; r < 4; ++r) {
                int prow = s * 16 + q * 4 + r;
                float h0 = fmaxf(acc0[r] + b1lds[dt0 * 16 + l15], 0.f);
                float h1 = fmaxf(acc1[r] + b1lds[dt1 * 16 + l15], 0.f);
                htile[prow * HS + dt0 * 16 + l15] = f2bf(h0);
                htile[prow * HS + dt1 * 16 + l15] = f2bf(h1);
            }
        }
        __syncthreads();

        // ---- GEMM2: Z[px][o] = sum_d h[px][d] * W2[o][d], + b2, sigmoid ----
        {
            const int dt0 = dh * 2, dt1 = dh * 2 + 1;
            f32x4 acc0 = {0.f, 0.f, 0.f, 0.f}, acc1 = {0.f, 0.f, 0.f, 0.f};
            const int arow  = (s * 16 + l15) * HS + q * 8;
            const int brow0 = (dt0 * 16 + l15) * HS + q * 8;
            const int brow1 = (dt1 * 16 + l15) * HS + q * 8;
            for (int kk = 0; kk < 64; kk += 32) {
                bf16x8 a   = *(const bf16x8*)&htile[arow + kk];
                bf16x8 bb0 = *(const bf16x8*)&w2lds[brow0 + kk];
                bf16x8 bb1 = *(const bf16x8*)&w2lds[brow1 + kk];
                acc0 = __builtin_amdgcn_mfma_f32_16x16x32_bf16(a, bb0, acc0, 0, 0, 0);
                acc1 = __builtin_amdgcn_mfma_f32_16x16x32_bf16(a, bb1, acc1, 0, 0, 0);
            }
            for (int r = 0; r < 4; ++r) {
                int prow = s * 16 + q * 4 + r;
                float z0 = acc0[r] + b2lds[dt0 * 16 + l15];
                float z1 = acc1[r] + b2lds[dt1 * 16 + l15];
                float f0 = 1.0f / (1.0f + exp2f(z0 * -1.44269504f));
                float f1 = 1.0f / (1.0f + exp2f(z1 * -1.44269504f));
                ftile[prow * HS + dt0 * 16 + l15] = f2bf(f0);
                ftile[prow * HS + dt1 * 16 + l15] = f2bf(f1);
            }
        }
        __syncthreads();

        // ---- per-pixel sum of f^2 (from the same bf16 f fed to GEMM3) ----
        if (t < 64) {
            float acc = 0.f;
            for (int d = 0; d < DD; ++d) { float v = bf2f(ftile[t * HS + d]); acc += v * v; }
            s2lds[t] = acc;
        }
        __syncthreads();

        // ---- GEMM3: xp = f . proto  ->  dist = s2 - 2 xp + p2, relu, min ----
        {
            const int arow = (s * 16 + l15) * HS + q * 8;
            bf16x8 a0 = *(const bf16x8*)&ftile[arow];
            bf16x8 a1 = *(const bf16x8*)&ftile[arow + 32];
            for (int pt = dh; pt < 13; pt += 2) {
                const int brow = (pt * 16 + l15) * HS + q * 8;
                bf16x8 bb0 = *(const bf16x8*)&protolds[brow];
                bf16x8 bb1 = *(const bf16x8*)&protolds[brow + 32];
                f32x4 acc = {0.f, 0.f, 0.f, 0.f};
                acc = __builtin_amdgcn_mfma_f32_16x16x32_bf16(a0, bb0, acc, 0, 0, 0);
                acc = __builtin_amdgcn_mfma_f32_16x16x32_bf16(a1, bb1, acc, 0, 0, 0);
                const int p = pt * 16 + l15;
                float m = __uint_as_float(0x7f800000u);
                for (int r = 0; r < 4; ++r) {
                    int pl = s * 16 + q * 4 + r;
                    if (px0 + pl < PIX) {
                        float dist = s2lds[pl] - 2.f * acc[r] + p2lds[p];
                        dist = fmaxf(dist, 0.f);
                        m = fminf(m, dist);
                    }
                }
                m = fminf(m, __shfl_xor(m, 16, 64));
                m = fminf(m, __shfl_xor(m, 32, 64));
                if (lane < 16) atomicMin(&bmin[p], __float_as_uint(m));
            }
        }
        __syncthreads();
    }

    // ---------------- epilogue: min_distances + logits ----------------
    if (t < NP) {
        out[NIMG * NCLS + (size_t)n * NP + t] = __uint_as_float(bmin[t]);
    }
    if (t < 320) {
        int c = t >> 5, j = t & 31;
        float acc = 0.f;
        for (int p = j; p < NP; p += 32)
            acc += __uint_as_float(bmin[p]) * lastW[c * NP + p];
        acc += __shfl_xor(acc, 1, 32);
        acc += __shfl_xor(acc, 2, 32);
        acc += __shfl_xor(acc, 4, 32);
        acc += __shfl_xor(acc, 8, 32);
        acc += __shfl_xor(acc, 16, 32);
        if (j == 0) out[(size_t)n * NCLS + c] = -acc + lastb[c];
    }
}

extern "C" void kernel_launch(void* const* d_in, const int* in_sizes, int n_in,
                              void* d_out, int out_size, void* d_ws, size_t ws_size,
                              hipStream_t stream) {
    const float* x     = (const float*)d_in[0];
    const float* W1    = (const float*)d_in[1];
    const float* b1    = (const float*)d_in[2];
    const float* W2    = (const float*)d_in[3];
    const float* b2    = (const float*)d_in[4];
    const float* proto = (const float*)d_in[5];
    const float* lastW = (const float*)d_in[6];
    const float* lastb = (const float*)d_in[7];
    float* out = (float*)d_out;

    proto_fused_kernel<<<dim3(NIMG), dim3(512), 0, stream>>>(
        x, W1, b1, W2, b2, proto, lastW, lastb, out);
}

// Round 2
// 312.335 us; speedup vs baseline: 1.1814x; 1.1814x over previous
//
#include <hip/hip_runtime.h>
#include <hip/hip_bf16.h>

#define NIMG 256
#define CIN  256
#define PIX  784
#define DD   64
#define NP   200
#define NPP  208   // prototypes padded to 13*16
#define NCLS 10

#define XS 264     // row stride (bf16) for xlds/w1lds: 132 dwords == 4 mod 32, 16B-aligned rows
#define HS 72      // row stride (bf16) for htile/ftile/w2lds/protolds: 36 dwords == 4 mod 32

typedef __attribute__((ext_vector_type(8))) short bf16x8;
typedef __attribute__((ext_vector_type(4))) float f32x4;
typedef __attribute__((ext_vector_type(4))) unsigned int u32x4;

__device__ __forceinline__ unsigned short f2bf(float f) {
    union { float f; unsigned int u; } v; v.f = f;
    unsigned int r = v.u + 0x7fffu + ((v.u >> 16) & 1u);   // RNE
    return (unsigned short)(r >> 16);
}

__device__ __forceinline__ unsigned int pk2(float a, float b) {
    __hip_bfloat162 p = __float22bfloat162_rn(make_float2(a, b));
    return *(unsigned int*)&p;
}

#define MFMA(a, b, c) __builtin_amdgcn_mfma_f32_16x16x32_bf16((a), (b), (c), 0, 0, 0)

__global__ __launch_bounds__(512, 2)
void proto_fused_kernel(const float* __restrict__ x,
                        const float* __restrict__ W1, const float* __restrict__ b1,
                        const float* __restrict__ W2, const float* __restrict__ b2,
                        const float* __restrict__ proto,
                        const float* __restrict__ lastW, const float* __restrict__ lastb,
                        float* __restrict__ out)
{
    __shared__ __align__(16) unsigned short xlds[64 * XS];      // 33.8 KB, [px][c]
    __shared__ __align__(16) unsigned short w1lds[64 * XS];     // 33.8 KB, [o][c]
    __shared__ __align__(16) unsigned short w2lds[64 * HS];     //  9.2 KB, [o][c]
    __shared__ __align__(16) unsigned short protolds[NPP * HS]; // 30.0 KB, [p][d]
    __shared__ __align__(16) unsigned short htile[64 * HS];     //  9.2 KB, [px][d]
    __shared__ __align__(16) unsigned short ftile[64 * HS];     //  9.2 KB, [px][d]
    __shared__ float p2lds[NPP];
    __shared__ float s2lds[2][64];      // per-half-wave partial sums of f^2
    __shared__ float b1lds[DD], b2lds[DD];
    __shared__ unsigned int bmin[NPP];

    const int n    = blockIdx.x;
    const int t    = threadIdx.x;
    const int lane = t & 63;
    const int q    = lane >> 4;     // quad row within wave
    const int l15  = lane & 15;
    const int wave = t >> 6;
    const int s    = wave & 3;      // pixel strip (16 px) within 64-px tile
    const int dh   = wave >> 2;     // which half of the d/proto tiles this wave owns
    const int dt0  = dh * 2, dt1 = dh * 2 + 1;

    // ---------------- one-time staging (contiguous-index writes: conflict-light) ----
    for (int i = 0; i < 32; ++i) {               // W1: 64x256
        int idx = t + i * 512;
        w1lds[(idx >> 8) * XS + (idx & 255)] = f2bf(W1[idx]);
    }
    for (int i = 0; i < 8; ++i) {                // W2: 64x64
        int idx = t + i * 512;
        w2lds[(idx >> 6) * HS + (idx & 63)] = f2bf(W2[idx]);
    }
    for (int i = 0; i < 25; ++i) {               // prototypes: 200x64
        int idx = t + i * 512;
        protolds[(idx >> 6) * HS + (idx & 63)] = f2bf(proto[idx]);
    }
    {   // zero pad prototype rows 200..207
        int p = NP + (t >> 6), d = t & 63;
        protolds[p * HS + d] = 0;
    }
    if (t < DD) { b1lds[t] = b1[t]; b2lds[t] = b2[t]; }
    if (t < NPP) {
        float acc = 0.f;
        if (t < NP) {
            for (int d = 0; d < DD; ++d) { float v = proto[t * DD + d]; acc += v * v; }
        }
        p2lds[t] = acc;
        bmin[t] = 0x7f800000u;   // +inf bits (dist >= 0: uint order == float order)
    }

    // ---- x-tile load/store: thread t handles 4 px (p4..p4+3) x 8 contiguous c ----
    const int p4  = (t & 15) * 4;
    const int cb8 = (t >> 4) * 8;
    const float* xn = x + (size_t)n * CIN * PIX;

    float4 pf[8];
    auto load_tile = [&](int px0) {
        #pragma unroll
        for (int j = 0; j < 8; ++j) {
            const float* src = xn + (size_t)(cb8 + j) * PIX + px0 + p4;
            float4 v;
            if (px0 + p4 + 3 < PIX) {
                v = *(const float4*)src;
            } else {
                v.x = (px0 + p4 + 0 < PIX) ? src[0] : 0.f;
                v.y = (px0 + p4 + 1 < PIX) ? src[1] : 0.f;
                v.z = (px0 + p4 + 2 < PIX) ? src[2] : 0.f;
                v.w = (px0 + p4 + 3 < PIX) ? src[3] : 0.f;
            }
            pf[j] = v;
        }
    };
    auto store_tile = [&]() {   // register transpose -> 4x ds_write_b128
        #pragma unroll
        for (int r = 0; r < 4; ++r) {
            u32x4 uv;
            uv.x = pk2(((const float*)&pf[0])[r], ((const float*)&pf[1])[r]);
            uv.y = pk2(((const float*)&pf[2])[r], ((const float*)&pf[3])[r]);
            uv.z = pk2(((const float*)&pf[4])[r], ((const float*)&pf[5])[r]);
            uv.w = pk2(((const float*)&pf[6])[r], ((const float*)&pf[7])[r]);
            *(u32x4*)&xlds[(p4 + r) * XS + cb8] = uv;
        }
    };

    // prologue: tile 0 into xlds, tile 1 in flight in pf
    load_tile(0);
    store_tile();
    load_tile(64);
    __syncthreads();

    // ---- hoist W1/W2 B-fragments into registers (reused all 13 tiles) ----
    bf16x8 w1f0[8], w1f1[8];
    #pragma unroll
    for (int kk = 0; kk < 8; ++kk) {
        w1f0[kk] = *(const bf16x8*)&w1lds[(dt0 * 16 + l15) * XS + kk * 32 + q * 8];
        w1f1[kk] = *(const bf16x8*)&w1lds[(dt1 * 16 + l15) * XS + kk * 32 + q * 8];
    }
    bf16x8 w2f0[2], w2f1[2];
    #pragma unroll
    for (int kk = 0; kk < 2; ++kk) {
        w2f0[kk] = *(const bf16x8*)&w2lds[(dt0 * 16 + l15) * HS + kk * 32 + q * 8];
        w2f1[kk] = *(const bf16x8*)&w2lds[(dt1 * 16 + l15) * HS + kk * 32 + q * 8];
    }

    // ---------------- main loop: 13 pixel tiles, 2 barriers each ----------------
    for (int tl = 0; tl < 13; ++tl) {
        const int px0 = tl * 64;

        // ---- phase 1: GEMM1 (reads xlds) -> htile ----
        {
            f32x4 acc0 = {0.f, 0.f, 0.f, 0.f}, acc1 = {0.f, 0.f, 0.f, 0.f};
            const int arow = (s * 16 + l15) * XS + q * 8;
            #pragma unroll
            for (int kk = 0; kk < 8; ++kk) {
                bf16x8 a = *(const bf16x8*)&xlds[arow + kk * 32];
                acc0 = MFMA(a, w1f0[kk], acc0);
                acc1 = MFMA(a, w1f1[kk], acc1);
            }
            #pragma unroll
            for (int r = 0; r < 4; ++r) {
                int prow = s * 16 + q * 4 + r;
                float h0 = fmaxf(acc0[r] + b1lds[dt0 * 16 + l15], 0.f);
                float h1 = fmaxf(acc1[r] + b1lds[dt1 * 16 + l15], 0.f);
                htile[prow * HS + dt0 * 16 + l15] = f2bf(h0);
                htile[prow * HS + dt1 * 16 + l15] = f2bf(h1);
            }
        }
        __syncthreads();

        // ---- phase 2: stage next x tile (xlds now free) + GEMM2 -> ftile, s2 ----
        if (tl < 12) store_tile();
        {
            f32x4 acc0 = {0.f, 0.f, 0.f, 0.f}, acc1 = {0.f, 0.f, 0.f, 0.f};
            const int arowH = (s * 16 + l15) * HS + q * 8;
            bf16x8 a0 = *(const bf16x8*)&htile[arowH];
            bf16x8 a1 = *(const bf16x8*)&htile[arowH + 32];
            acc0 = MFMA(a0, w2f0[0], acc0);
            acc0 = MFMA(a1, w2f0[1], acc0);
            acc1 = MFMA(a0, w2f1[0], acc1);
            acc1 = MFMA(a1, w2f1[1], acc1);
            #pragma unroll
            for (int r = 0; r < 4; ++r) {
                int prow = s * 16 + q * 4 + r;
                float z0 = acc0[r] + b2lds[dt0 * 16 + l15];
                float z1 = acc1[r] + b2lds[dt1 * 16 + l15];
                float f0 = __builtin_amdgcn_rcpf(1.0f + __builtin_amdgcn_exp2f(z0 * -1.44269504f));
                float f1 = __builtin_amdgcn_rcpf(1.0f + __builtin_amdgcn_exp2f(z1 * -1.44269504f));
                ftile[prow * HS + dt0 * 16 + l15] = f2bf(f0);
                ftile[prow * HS + dt1 * 16 + l15] = f2bf(f1);
                // s^2 partial: sum over this half-wave's 32 channels, reduce over l15
                float v = f0 * f0 + f1 * f1;
                v += __shfl_xor(v, 1, 64);
                v += __shfl_xor(v, 2, 64);
                v += __shfl_xor(v, 4, 64);
                v += __shfl_xor(v, 8, 64);
                if (l15 == 0) s2lds[dh][prow] = v;
            }
        }
        __syncthreads();

        // ---- phase 3: prefetch tile tl+2, GEMM3 distances + min ----
        if (tl < 11) load_tile((tl + 2) * 64);
        {
            const int arowF = (s * 16 + l15) * HS + q * 8;
            bf16x8 a0 = *(const bf16x8*)&ftile[arowF];
            bf16x8 a1 = *(const bf16x8*)&ftile[arowF + 32];
            float s2v[4];
            bool  vmask[4];
            #pragma unroll
            for (int r = 0; r < 4; ++r) {
                int pl = s * 16 + q * 4 + r;
                s2v[r]   = s2lds[0][pl] + s2lds[1][pl];
                vmask[r] = (px0 + pl < PIX);
            }
            for (int pt = dh; pt < 13; pt += 2) {
                const int brow = (pt * 16 + l15) * HS + q * 8;
                bf16x8 bb0 = *(const bf16x8*)&protolds[brow];
                bf16x8 bb1 = *(const bf16x8*)&protolds[brow + 32];
                f32x4 acc = {0.f, 0.f, 0.f, 0.f};
                acc = MFMA(a0, bb0, acc);
                acc = MFMA(a1, bb1, acc);
                const int p = pt * 16 + l15;
                const float p2v = p2lds[p];
                float m = 1e30f;
                #pragma unroll
                for (int r = 0; r < 4; ++r) {
                    float dist = fmaxf(s2v[r] - 2.f * acc[r] + p2v, 0.f);
                    if (vmask[r]) m = fminf(m, dist);
                }
                m = fminf(m, __shfl_xor(m, 16, 64));
                m = fminf(m, __shfl_xor(m, 32, 64));
                if (lane < 16) atomicMin(&bmin[p], __float_as_uint(m));
            }
        }
        // no barrier needed: next GEMM1 reads xlds (written before phase-2 sync);
        // it writes htile (last read before phase-2 sync); GEMM3 touches neither.
    }
    __syncthreads();

    // ---------------- epilogue: min_distances + logits ----------------
    if (t < NP) {
        out[NIMG * NCLS + (size_t)n * NP + t] = __uint_as_float(bmin[t]);
    }
    if (t < 320) {
        int c = t >> 5, j = t & 31;
        float acc = 0.f;
        for (int p = j; p < NP; p += 32)
            acc += __uint_as_float(bmin[p]) * lastW[c * NP + p];
        acc += __shfl_xor(acc, 1, 32);
        acc += __shfl_xor(acc, 2, 32);
        acc += __shfl_xor(acc, 4, 32);
        acc += __shfl_xor(acc, 8, 32);
        acc += __shfl_xor(acc, 16, 32);
        if (j == 0) out[(size_t)n * NCLS + c] = -acc + lastb[c];
    }
}

extern "C" void kernel_launch(void* const* d_in, const int* in_sizes, int n_in,
                              void* d_out, int out_size, void* d_ws, size_t ws_size,
                              hipStream_t stream) {
    const float* x     = (const float*)d_in[0];
    const float* W1    = (const float*)d_in[1];
    const float* b1    = (const float*)d_in[2];
    const float* W2    = (const float*)d_in[3];
    const float* b2    = (const float*)d_in[4];
    const float* proto = (const float*)d_in[5];
    const float* lastW = (const float*)d_in[6];
    const float* lastb = (const float*)d_in[7];
    float* out = (float*)d_out;

    proto_fused_kernel<<<dim3(NIMG), dim3(512), 0, stream>>>(
        x, W1, b1, W2, b2, proto, lastW, lastb, out);
}

// Round 4
// 308.861 us; speedup vs baseline: 1.1947x; 1.0112x over previous
//
#include <hip/hip_runtime.h>
#include <hip/hip_bf16.h>

#define NIMG 256
#define CIN  256
#define PIX  784
#define DD   64
#define NP   200
#define NPP  208   // prototypes padded to 13*16
#define NCLS 10

#define XS 264     // row stride (bf16) xlds/w1lds: 132 dw; quad = (row + c8grp) & 7
#define HS 72      // row stride (bf16) htile/ftile/w2lds

typedef __attribute__((ext_vector_type(8))) short bf16x8;
typedef __attribute__((ext_vector_type(4))) float f32x4;
typedef __attribute__((ext_vector_type(4))) unsigned int u32x4;

__device__ __forceinline__ unsigned short f2bf(float f) {
    union { float f; unsigned int u; } v; v.f = f;
    unsigned int r = v.u + 0x7fffu + ((v.u >> 16) & 1u);   // RNE
    return (unsigned short)(r >> 16);
}
__device__ __forceinline__ unsigned int pk2(float a, float b) {
    __hip_bfloat162 p = __float22bfloat162_rn(make_float2(a, b));
    return *(unsigned int*)&p;
}

#define MFMA(a, b, c) __builtin_amdgcn_mfma_f32_16x16x32_bf16((a), (b), (c), 0, 0, 0)

__global__ __launch_bounds__(512, 2)
void proto_fused_kernel(const float* __restrict__ x,
                        const float* __restrict__ W1, const float* __restrict__ b1,
                        const float* __restrict__ W2, const float* __restrict__ b2,
                        const float* __restrict__ proto,
                        const float* __restrict__ lastW, const float* __restrict__ lastb,
                        float* __restrict__ out)
{
    __shared__ __align__(16) unsigned short xlds[64 * XS];      // 33.8 KB, [px][c]
    __shared__ __align__(16) unsigned short w1lds[64 * XS];     // 33.8 KB, [o][c]
    __shared__ __align__(16) unsigned short w2lds[64 * HS];     //  9.2 KB, [o][c]
    __shared__ __align__(16) unsigned short htile[64 * HS];     //  9.2 KB, [px][d]
    __shared__ __align__(16) unsigned short ftile[64 * HS];     //  9.2 KB, [px][d]
    __shared__ float p2lds[NPP];
    __shared__ float s2lds[2][64];      // per-half partial sums of f^2
    __shared__ float b1lds[DD], b2lds[DD];
    __shared__ unsigned int bmin[NPP];

    const int n    = blockIdx.x;
    const int t    = threadIdx.x;
    const int lane = t & 63;
    const int q    = lane >> 4;     // quad row within wave
    const int l15  = lane & 15;
    const int wave = t >> 6;
    const int s    = wave & 3;      // pixel strip (16 px) within 64-px tile
    const int dh   = wave >> 2;     // half of the d/proto tiles this wave owns
    const int dt0  = dh * 2, dt1 = dh * 2 + 1;

    // ---------------- one-time staging ----------------
    for (int i = 0; i < 32; ++i) {               // W1: 64x256
        int idx = t + i * 512;
        w1lds[(idx >> 8) * XS + (idx & 255)] = f2bf(W1[idx]);
    }
    for (int i = 0; i < 8; ++i) {                // W2: 64x64
        int idx = t + i * 512;
        w2lds[(idx >> 6) * HS + (idx & 63)] = f2bf(W2[idx]);
    }
    if (t < DD) { b1lds[t] = b1[t]; b2lds[t] = b2[t]; }
    if (t < NPP) {
        float acc = 0.f;
        if (t < NP) {
            const float4* pp = (const float4*)(proto + t * DD);
            #pragma unroll
            for (int i = 0; i < 16; ++i) {
                float4 v = pp[i];
                acc += v.x * v.x + v.y * v.y + v.z * v.z + v.w * v.w;
            }
        }
        p2lds[t] = acc;
        bmin[t] = 0x7f800000u;   // +inf bits (dist >= 0: uint order == float order)
    }

    // ---- prototype B-fragments: straight from global into registers ----
    bf16x8 pb0[7], pb1[7];
    #pragma unroll
    for (int it = 0; it < 7; ++it) {
        int pt = dh + 2 * it;
        int p  = pt * 16 + l15;
        int pr = (p < NP) ? p : (NP - 1);        // clamp pads (results discarded)
        const float4* src = (const float4*)(proto + (size_t)pr * DD + q * 8);
        float4 a = src[0], b = src[1];           // k = q*8 .. q*8+7
        float4 c = src[8], d = src[9];           // k = 32 + q*8 ..
        union { u32x4 u; bf16x8 h; } cv0, cv1;
        cv0.u.x = pk2(a.x, a.y); cv0.u.y = pk2(a.z, a.w);
        cv0.u.z = pk2(b.x, b.y); cv0.u.w = pk2(b.z, b.w);
        cv1.u.x = pk2(c.x, c.y); cv1.u.y = pk2(c.z, c.w);
        cv1.u.z = pk2(d.x, d.y); cv1.u.w = pk2(d.z, d.w);
        pb0[it] = cv0.h; pb1[it] = cv1.h;
    }

    // ---- x-tile load/store lane map: p4=((t>>2)&15)*4, c8grp=(t&3)|(wave<<2) ----
    // store quad = (row + c8grp) & 7: rows step 4, c8grp steps 1 within each
    // 4-lane cluster -> every 8 consecutive lanes cover all 8 bank quads.
    const int p4   = ((t >> 2) & 15) * 4;
    const int c8i  = (t & 3) | ((t >> 6) << 2);  // 0..31
    const int c8   = c8i * 8;
    const float* xn = x + (size_t)n * CIN * PIX;

    float4 pf[8];
    auto load_tile = [&](int px0) {
        #pragma unroll
        for (int j = 0; j < 8; ++j) {
            const float* src = xn + (size_t)(c8 + j) * PIX + px0 + p4;
            float4 v;
            if (px0 + p4 + 3 < PIX) {
                v = *(const float4*)src;
            } else {
                v.x = (px0 + p4 + 0 < PIX) ? src[0] : 0.f;
                v.y = (px0 + p4 + 1 < PIX) ? src[1] : 0.f;
                v.z = (px0 + p4 + 2 < PIX) ? src[2] : 0.f;
                v.w = (px0 + p4 + 3 < PIX) ? src[3] : 0.f;
            }
            pf[j] = v;
        }
    };
    auto store_tile = [&]() {   // register transpose -> 4x ds_write_b128
        #pragma unroll
        for (int r = 0; r < 4; ++r) {
            u32x4 uv;
            uv.x = pk2(((const float*)&pf[0])[r], ((const float*)&pf[1])[r]);
            uv.y = pk2(((const float*)&pf[2])[r], ((const float*)&pf[3])[r]);
            uv.z = pk2(((const float*)&pf[4])[r], ((const float*)&pf[5])[r]);
            uv.w = pk2(((const float*)&pf[6])[r], ((const float*)&pf[7])[r]);
            *(u32x4*)&xlds[(p4 + r) * XS + c8] = uv;
        }
    };

    // prologue: tile 0 into xlds, tile 1 in flight in pf
    load_tile(0);
    store_tile();
    load_tile(64);
    __syncthreads();

    // ---- hoist W1/W2 B-fragments + p2 into registers ----
    bf16x8 w1f0[8], w1f1[8];
    #pragma unroll
    for (int kk = 0; kk < 8; ++kk) {
        w1f0[kk] = *(const bf16x8*)&w1lds[(dt0 * 16 + l15) * XS + kk * 32 + q * 8];
        w1f1[kk] = *(const bf16x8*)&w1lds[(dt1 * 16 + l15) * XS + kk * 32 + q * 8];
    }
    bf16x8 w2f0[2], w2f1[2];
    #pragma unroll
    for (int kk = 0; kk < 2; ++kk) {
        w2f0[kk] = *(const bf16x8*)&w2lds[(dt0 * 16 + l15) * HS + kk * 32 + q * 8];
        w2f1[kk] = *(const bf16x8*)&w2lds[(dt1 * 16 + l15) * HS + kk * 32 + q * 8];
    }
    float p2r[7];
    #pragma unroll
    for (int it = 0; it < 7; ++it) {
        int pidx = (dh + 2 * it) * 16 + l15;
        p2r[it] = p2lds[pidx < NPP ? pidx : (NPP - 1)];
    }

    float rmin[7];
    #pragma unroll
    for (int it = 0; it < 7; ++it) rmin[it] = 1e30f;

    // ---------------- main loop: 13 pixel tiles, 2 barriers each ----------------
    for (int tl = 0; tl < 13; ++tl) {
        const int px0 = tl * 64;

        // ---- P1: GEMM1 (reads xlds) -> htile ----
        {
            f32x4 acc0 = {0.f, 0.f, 0.f, 0.f}, acc1 = {0.f, 0.f, 0.f, 0.f};
            const int arow = (s * 16 + l15) * XS + q * 8;
            #pragma unroll
            for (int kk = 0; kk < 8; ++kk) {
                bf16x8 a = *(const bf16x8*)&xlds[arow + kk * 32];
                acc0 = MFMA(a, w1f0[kk], acc0);
                acc1 = MFMA(a, w1f1[kk], acc1);
            }
            #pragma unroll
            for (int r = 0; r < 4; ++r) {
                int prow = s * 16 + q * 4 + r;
                float h0 = fmaxf(acc0[r] + b1lds[dt0 * 16 + l15], 0.f);
                float h1 = fmaxf(acc1[r] + b1lds[dt1 * 16 + l15], 0.f);
                htile[prow * HS + dt0 * 16 + l15] = f2bf(h0);
                htile[prow * HS + dt1 * 16 + l15] = f2bf(h1);
            }
        }
        __syncthreads();

        // ---- P2: stage next x tile, prefetch tile tl+2, GEMM2 -> ftile, s2 ----
        if (tl < 12) store_tile();
        if (tl < 11) load_tile((tl + 2) * 64);
        {
            f32x4 acc0 = {0.f, 0.f, 0.f, 0.f}, acc1 = {0.f, 0.f, 0.f, 0.f};
            const int arowH = (s * 16 + l15) * HS + q * 8;
            bf16x8 a0 = *(const bf16x8*)&htile[arowH];
            bf16x8 a1 = *(const bf16x8*)&htile[arowH + 32];
            acc0 = MFMA(a0, w2f0[0], acc0);
            acc0 = MFMA(a1, w2f0[1], acc0);
            acc1 = MFMA(a0, w2f1[0], acc1);
            acc1 = MFMA(a1, w2f1[1], acc1);
            #pragma unroll
            for (int r = 0; r < 4; ++r) {
                int prow = s * 16 + q * 4 + r;
                float z0 = acc0[r] + b2lds[dt0 * 16 + l15];
                float z1 = acc1[r] + b2lds[dt1 * 16 + l15];
                float f0 = __builtin_amdgcn_rcpf(1.0f + __builtin_amdgcn_exp2f(z0 * -1.44269504f));
                float f1 = __builtin_amdgcn_rcpf(1.0f + __builtin_amdgcn_exp2f(z1 * -1.44269504f));
                ftile[prow * HS + dt0 * 16 + l15] = f2bf(f0);
                ftile[prow * HS + dt1 * 16 + l15] = f2bf(f1);
                float v = f0 * f0 + f1 * f1;
                v += __shfl_xor(v, 1, 64);
                v += __shfl_xor(v, 2, 64);
                v += __shfl_xor(v, 4, 64);
                v += __shfl_xor(v, 8, 64);
                if (l15 == 0)
                    s2lds[dh][prow] = (px0 + prow < PIX) ? v : 1e30f;  // pad poison
            }
        }
        __syncthreads();

        // ---- P3: GEMM3 distances -> per-lane running min (regs only) ----
        {
            const int arowF = (s * 16 + l15) * HS + q * 8;
            bf16x8 a0 = *(const bf16x8*)&ftile[arowF];
            bf16x8 a1 = *(const bf16x8*)&ftile[arowF + 32];
            float s2v[4];
            #pragma unroll
            for (int r = 0; r < 4; ++r) {
                int pl = s * 16 + q * 4 + r;
                s2v[r] = s2lds[0][pl] + s2lds[1][pl];
            }
            #pragma unroll
            for (int it = 0; it < 7; ++it) {
                f32x4 acc = {0.f, 0.f, 0.f, 0.f};
                acc = MFMA(a0, pb0[it], acc);
                acc = MFMA(a1, pb1[it], acc);
                float m = 1e30f;
                #pragma unroll
                for (int r = 0; r < 4; ++r) {
                    float dist = fmaxf(s2v[r] - 2.f * acc[r] + p2r[it], 0.f);
                    m = fminf(m, dist);
                }
                rmin[it] = fminf(rmin[it], m);
            }
        }
        // no barrier: next P1 reads xlds (written pre-P2-barrier), writes htile
        // (last read pre-P2-barrier); P3 touched neither. (Empirically validated in R2.)
    }

    // ---- final min reduction: regs -> bmin ----
    #pragma unroll
    for (int it = 0; it < 7; ++it) {
        int pt = dh + 2 * it;
        if (pt < 13) {
            float m = rmin[it];
            m = fminf(m, __shfl_xor(m, 16, 64));
            m = fminf(m, __shfl_xor(m, 32, 64));
            if (lane < 16) atomicMin(&bmin[pt * 16 + l15], __float_as_uint(m));
        }
    }
    __syncthreads();

    // ---------------- epilogue: min_distances + logits ----------------
    if (t < NP) {
        out[NIMG * NCLS + (size_t)n * NP + t] = __uint_as_float(bmin[t]);
    }
    if (t < 320) {
        int c = t >> 5, j = t & 31;
        float acc = 0.f;
        for (int p = j; p < NP; p += 32)
            acc += __uint_as_float(bmin[p]) * lastW[c * NP + p];
        acc += __shfl_xor(acc, 1, 32);
        acc += __shfl_xor(acc, 2, 32);
        acc += __shfl_xor(acc, 4, 32);
        acc += __shfl_xor(acc, 8, 32);
        acc += __shfl_xor(acc, 16, 32);
        if (j == 0) out[(size_t)n * NCLS + c] = -acc + lastb[c];
    }
}

extern "C" void kernel_launch(void* const* d_in, const int* in_sizes, int n_in,
                              void* d_out, int out_size, void* d_ws, size_t ws_size,
                              hipStream_t stream) {
    const float* x     = (const float*)d_in[0];
    const float* W1    = (const float*)d_in[1];
    const float* b1    = (const float*)d_in[2];
    const float* W2    = (const float*)d_in[3];
    const float* b2    = (const float*)d_in[4];
    const float* proto = (const float*)d_in[5];
    const float* lastW = (const float*)d_in[6];
    const float* lastb = (const float*)d_in[7];
    float* out = (float*)d_out;

    proto_fused_kernel<<<dim3(NIMG), dim3(512), 0, stream>>>(
        x, W1, b1, W2, b2, proto, lastW, lastb, out);
}